// Round 2
// baseline (639.570 us; speedup 1.0000x reference)
//
#include <hip/hip_runtime.h>
#include <math.h>

// x is (8, 4096, 3*1024) fp32. Reformulated as first-order linear recurrence:
//   f_t = 1 - sigmoid(x_i) ; kv_t = tanh(x_x) * sigmoid(x_i) ; a_t = prod f
//   y_t = f_t * y_{t-1} + kv_t * a_t/(a_t+eps) ; out = tanh(y)*sigmoid(x_o)
#define BATCH 8
#define TLEN  4096
#define DH    1024
#define ROW   (3 * DH)          // 3072 floats per (b,t) row
#define EPS   1e-4f
#define CHUNK 32                // steps per chunk
#define NCHUNK (TLEN / CHUNK)   // 128
#define NLANE (BATCH * DH)      // 8192 independent scan lanes

// v_rcp_f32 (~1 ulp) instead of IEEE divide: tolerance is 1.3e-2, and the
// full div sequence (v_div_scale/fmas/fixup) is ~8-10 VALU instrs each.
__device__ __forceinline__ float frcp(float x) { return __builtin_amdgcn_rcpf(x); }
__device__ __forceinline__ float fsig(float z)  { return frcp(1.0f + __expf(-z)); }
__device__ __forceinline__ float ftanhf_(float v) { return 1.0f - 2.0f * frcp(__expf(2.0f * v) + 1.0f); }

// K1: per-(lane-quad, chunk) product of forget gates, float4 loads.
__global__ void k_chunkprod(const float* __restrict__ x, float* __restrict__ P) {
    const int tid = threadIdx.x;            // 0..255, handles d = 4*tid..4*tid+3
    const int b = blockIdx.x, c = blockIdx.y;
    const float* xg = x + (size_t)(b * TLEN + c * CHUNK) * ROW + DH + 4 * tid;
    float4 p = make_float4(1.f, 1.f, 1.f, 1.f);
#pragma unroll 4
    for (int t = 0; t < CHUNK; ++t) {
        float4 z = *(const float4*)(xg + (size_t)t * ROW);
        p.x *= frcp(1.0f + __expf(z.x));    // f = 1 - sigmoid(z) = 1/(1+e^z)
        p.y *= frcp(1.0f + __expf(z.y));
        p.z *= frcp(1.0f + __expf(z.z));
        p.w *= frcp(1.0f + __expf(z.w));
    }
    *(float4*)(P + (size_t)c * NLANE + b * DH + 4 * tid) = p;
}

// K2: per-lane exclusive scan of chunk products -> incoming cumprod a_in.
__global__ void k_scan_a(const float* __restrict__ P, float* __restrict__ Ain) {
    const int lane = blockIdx.x * blockDim.x + threadIdx.x;  // 0..8191
    float a = 1.0f;
#pragma unroll 8
    for (int c = 0; c < NCHUNK; ++c) {
        Ain[(size_t)c * NLANE + lane] = a;
        a *= P[(size_t)c * NLANE + lane];
    }
}

// One recurrence step for one float4 component.
#define STEP(comp)                                                         \
    {                                                                      \
        float f  = frcp(1.0f + __expf(zi.comp));                           \
        float kv = ftanhf_(zx.comp) * (1.0f - f);                          \
        a.comp *= f;                                                       \
        float r = a.comp * frcp(a.comp + EPS);                             \
        y.comp = f * y.comp + kv * r;                                      \
    }

// K3: per-(lane-quad, chunk) local recurrence with y_in = 0 given a_in -> Q.
__global__ void k_partial(const float* __restrict__ x,
                          const float* __restrict__ Ain,
                          float* __restrict__ Q) {
    const int tid = threadIdx.x;
    const int b = blockIdx.x, c = blockIdx.y;
    const int lane = b * DH + 4 * tid;
    const float* xp = x + (size_t)(b * TLEN + c * CHUNK) * ROW + 4 * tid;
    float4 a = *(const float4*)(Ain + (size_t)c * NLANE + lane);
    float4 y = make_float4(0.f, 0.f, 0.f, 0.f);
#pragma unroll 2
    for (int t = 0; t < CHUNK; ++t) {
        const float* row = xp + (size_t)t * ROW;
        float4 zx = *(const float4*)(row);
        float4 zi = *(const float4*)(row + DH);
        STEP(x) STEP(y) STEP(z) STEP(w)
    }
    *(float4*)(Q + (size_t)c * NLANE + lane) = y;
}

// K4: per-lane exclusive scan of (P, Q) -> incoming y per chunk.
__global__ void k_scan_y(const float* __restrict__ P,
                         const float* __restrict__ Q,
                         float* __restrict__ Yin) {
    const int lane = blockIdx.x * blockDim.x + threadIdx.x;
    float y = 0.0f;
#pragma unroll 8
    for (int c = 0; c < NCHUNK; ++c) {
        Yin[(size_t)c * NLANE + lane] = y;
        y = P[(size_t)c * NLANE + lane] * y + Q[(size_t)c * NLANE + lane];
    }
}

// K5: recompute chunk with known (a_in, y_in); apply output gate, write out.
__global__ void k_final(const float* __restrict__ x,
                        const float* __restrict__ Ain,
                        const float* __restrict__ Yin,
                        float* __restrict__ out) {
    const int tid = threadIdx.x;
    const int b = blockIdx.x, c = blockIdx.y;
    const int lane = b * DH + 4 * tid;
    const float* xp = x + (size_t)(b * TLEN + c * CHUNK) * ROW + 4 * tid;
    float* op = out + (size_t)(b * TLEN + c * CHUNK) * DH + 4 * tid;
    float4 a = *(const float4*)(Ain + (size_t)c * NLANE + lane);
    float4 y = *(const float4*)(Yin + (size_t)c * NLANE + lane);
#pragma unroll 2
    for (int t = 0; t < CHUNK; ++t) {
        const float* row = xp + (size_t)t * ROW;
        float4 zx = *(const float4*)(row);
        float4 zi = *(const float4*)(row + DH);
        float4 zo = *(const float4*)(row + 2 * DH);
        STEP(x) STEP(y) STEP(z) STEP(w)
        float4 o;
        o.x = ftanhf_(y.x) * fsig(zo.x);
        o.y = ftanhf_(y.y) * fsig(zo.y);
        o.z = ftanhf_(y.z) * fsig(zo.z);
        o.w = ftanhf_(y.w) * fsig(zo.w);
        *(float4*)(op + (size_t)t * DH) = o;
    }
}

extern "C" void kernel_launch(void* const* d_in, const int* in_sizes, int n_in,
                              void* d_out, int out_size, void* d_ws, size_t ws_size,
                              hipStream_t stream) {
    const float* x = (const float*)d_in[0];
    float* out = (float*)d_out;

    // Workspace: 4 buffers of NCHUNK*NLANE fp32 = 4 * 4 MB = 16 MB.
    float* P   = (float*)d_ws;
    float* Ain = P   + (size_t)NCHUNK * NLANE;
    float* Q   = Ain + (size_t)NCHUNK * NLANE;
    float* Yin = Q   + (size_t)NCHUNK * NLANE;

    dim3 blk(256);
    dim3 grd(BATCH, NCHUNK);             // 8 x 128 = 1024 blocks, 4 waves each
    dim3 sblk(256);
    dim3 sgrd(NLANE / 256);              // 32 blocks

    k_chunkprod<<<grd, blk, 0, stream>>>(x, P);
    k_scan_a<<<sgrd, sblk, 0, stream>>>(P, Ain);
    k_partial<<<grd, blk, 0, stream>>>(x, Ain, Q);
    k_scan_y<<<sgrd, sblk, 0, stream>>>(P, Q, Yin);
    k_final<<<grd, blk, 0, stream>>>(x, Ain, Yin, out);
}